// Round 1
// baseline (360.816 us; speedup 1.0000x reference)
//
#include <hip/hip_runtime.h>
#include <hip/hip_bf16.h>
#include <cstdint>

// LSTMCell B=8192, IN=H=1024, fp32 in/out.
// R4: port of the verified 256x256 8-phase counted-vmcnt GEMM template
// (T2 swizzle + T3/T4 counted vmcnt + T5 setprio), fused LSTM epilogue.
//  - 16x16x32 bf16 MFMA, 8 waves (2M x 4N), wave tile 128x64, acc[8][4].
//  - Gate permutation p = (j>>4)*64 + gate*16 + (j&15): the 4 n-fragments
//    of a wave are the 4 gates of the same 16 j's -> lane-local epilogue.
//  - LDS 128 KiB: As/Bs [2 buf][2 khalf][256 rows][32 cols], XOR swizzle
//    slot ^ ((row>>1)&3) on 64B rows; conflict-free ds_read_b128.
//  - 4 phases/K-tile: {ds_read frags | stage 1 unit | barrier | lgkmcnt(0)
//    | setprio(1) 16 MFMA setprio(0) | [vmcnt(8) on odd phases] | barrier}.
//    Staging runs 5-6 phases ahead; vmcnt never drains to 0 in main loop.

#define B_DIM 8192
#define H_DIM 1024
#define K2    2048   // IN + H
#define N4    4096   // 4 * H
#define BK    64
#define BM    256
#define BN    256
#define NT    (K2 / BK)   // 32 K-tiles (must be even; peeled tail assumes it)

typedef __bf16 bf16x8 __attribute__((ext_vector_type(8)));
typedef float  f32x4  __attribute__((ext_vector_type(4)));

__device__ __forceinline__ void async_load16(const __bf16* g, __bf16* l) {
  __builtin_amdgcn_global_load_lds(
      (__attribute__((address_space(1))) void*)(g),
      (__attribute__((address_space(3))) void*)(l),
      16, 0, 0);
}

__device__ __forceinline__ float sigm(float x) {
  return 1.0f / (1.0f + __expf(-x));
}
__device__ __forceinline__ float tanh_fast(float x) {
  return 2.0f / (1.0f + __expf(-2.0f * x)) - 1.0f;
}

// ---------------- cast A = [x | h] -> bf16 [8192][2048] ----------------
__global__ void cast_a(const float* __restrict__ x, const float* __restrict__ h,
                       __bf16* __restrict__ A) {
  int row = blockIdx.x;
  int k = threadIdx.x << 3;  // 0..2040 step 8
  const float* src = (k < H_DIM) ? (x + (size_t)row * H_DIM + k)
                                 : (h + (size_t)row * H_DIM + (k - H_DIM));
  float4 v0 = *(const float4*)src;
  float4 v1 = *(const float4*)(src + 4);
  bf16x8 o;
  o[0] = (__bf16)v0.x; o[1] = (__bf16)v0.y; o[2] = (__bf16)v0.z; o[3] = (__bf16)v0.w;
  o[4] = (__bf16)v1.x; o[5] = (__bf16)v1.y; o[6] = (__bf16)v1.z; o[7] = (__bf16)v1.w;
  *(bf16x8*)&A[(size_t)row * K2 + k] = o;
}

// ------------- cast + transpose + permute weights -> Bt [4096][2048] -------------
// Bt row p = (j>>4)*64 + gate*16 + (j&15); Bt[p][k] = W_cat[k][gate-col j]
// grid: (K2/64, H/32, 4 gates), block 256
__global__ void cast_w(const float* __restrict__ Wii, const float* __restrict__ Wif,
                       const float* __restrict__ Wig, const float* __restrict__ Wio,
                       const float* __restrict__ Whi, const float* __restrict__ Whf,
                       const float* __restrict__ Whg, const float* __restrict__ Who,
                       __bf16* __restrict__ Bt) {
  __shared__ float tile[64][33];
  int k0 = blockIdx.x * 64;
  int j0 = blockIdx.y * 32;
  int gate = blockIdx.z;
  const float* Wi[4] = {Wii, Wif, Wig, Wio};
  const float* Wh[4] = {Whi, Whf, Whg, Who};
  const float* W = (k0 < H_DIM) ? Wi[gate] : Wh[gate];
  int kb = (k0 < H_DIM) ? k0 : (k0 - H_DIM);

  int col = threadIdx.x & 31;
  int rr  = threadIdx.x >> 5;  // 0..7
#pragma unroll
  for (int p = 0; p < 8; ++p)
    tile[p * 8 + rr][col] = W[(size_t)(kb + p * 8 + rr) * H_DIM + j0 + col];
  __syncthreads();

  int jj = threadIdx.x >> 3;   // 0..31
  int ko = threadIdx.x & 7;    // 0..7 (8 k's each)
  int j = j0 + jj;
  int p = ((j >> 4) << 6) + (gate << 4) + (j & 15);
  bf16x8 o;
#pragma unroll
  for (int t = 0; t < 8; ++t) o[t] = (__bf16)tile[ko * 8 + t][jj];
  *(bf16x8*)&Bt[(size_t)p * K2 + k0 + ko * 8] = o;
}

// ---------------- fused GEMM + LSTM gate epilogue (8-phase template) ----------------
// grid: 512 blocks (32 M-tiles x 16 N-tiles), block 512 (8 waves, 2M x 4N)

#define STAGE_A(D, KH, TT) do { \
    async_load16(gA0 + (size_t)(TT) * 64 + (KH) * 32, &As_s[D][KH][wave << 9]); \
    async_load16(gA1 + (size_t)(TT) * 64 + (KH) * 32, &As_s[D][KH][4096 + (wave << 9)]); \
  } while (0)
#define STAGE_B(D, KH, TT) do { \
    async_load16(gB0 + (size_t)(TT) * 64 + (KH) * 32, &Bs_s[D][KH][wave << 9]); \
    async_load16(gB1 + (size_t)(TT) * 64 + (KH) * 32, &Bs_s[D][KH][4096 + (wave << 9)]); \
  } while (0)

#define LOADA(D, KK, MH) do { \
    const __bf16* ap_ = &As_s[D][KK][(wm << 12) + ((MH) << 11) + lane_part]; \
    aF[0] = *(const bf16x8*)(ap_); \
    aF[1] = *(const bf16x8*)(ap_ + 512); \
    aF[2] = *(const bf16x8*)(ap_ + 1024); \
    aF[3] = *(const bf16x8*)(ap_ + 1536); \
  } while (0)
#define LOADB(D, KK) do { \
    const __bf16* bp_ = &Bs_s[D][KK][(wn << 11) + lane_part]; \
    bF[0] = *(const bf16x8*)(bp_); \
    bF[1] = *(const bf16x8*)(bp_ + 512); \
    bF[2] = *(const bf16x8*)(bp_ + 1024); \
    bF[3] = *(const bf16x8*)(bp_ + 1536); \
  } while (0)

// barrier; wait own ds_reads; fence scheduler (rule #18 insurance)
#define BARW() do { \
    __builtin_amdgcn_s_barrier(); \
    asm volatile("s_waitcnt lgkmcnt(0)" ::: "memory"); \
    __builtin_amdgcn_sched_barrier(0); \
  } while (0)
#define ENDBAR() __builtin_amdgcn_s_barrier()
#define GATE8() asm volatile("s_waitcnt vmcnt(8)" ::: "memory")
#define GATE4() asm volatile("s_waitcnt vmcnt(4)" ::: "memory")
#define GATE0() asm volatile("s_waitcnt vmcnt(0)" ::: "memory")

#define MFMA_Q(MH) do { \
    __builtin_amdgcn_s_setprio(1); \
    _Pragma("unroll") \
    for (int i2 = 0; i2 < 4; ++i2) { \
      _Pragma("unroll") \
      for (int n2 = 0; n2 < 4; ++n2) \
        acc[(MH) * 4 + i2][n2] = __builtin_amdgcn_mfma_f32_16x16x32_bf16( \
            aF[i2], bF[n2], acc[(MH) * 4 + i2][n2], 0, 0, 0); \
    } \
    __builtin_amdgcn_s_setprio(0); \
  } while (0)

__global__ __launch_bounds__(512, 2) void lstm_gemm(
    const __bf16* __restrict__ A,    // [8192][2048]
    const __bf16* __restrict__ Bt,   // [4096][2048] permuted rows
    const float* __restrict__ c,
    const float* __restrict__ bi, const float* __restrict__ bf_,
    const float* __restrict__ bg, const float* __restrict__ bo,
    float* __restrict__ out_c, float* __restrict__ out_h) {
  // [buf][khalf][256 rows][32 cols] bf16; row = 64 B = 4 x 16B slots.
  // phys slot s of row r holds global k-segment s ^ ((r>>1)&3).
  __shared__ __align__(16) __bf16 As_s[2][2][256 * 32];   // 64 KB
  __shared__ __align__(16) __bf16 Bs_s[2][2][256 * 32];   // 64 KB

  // bijective XCD swizzle (512 % 8 == 0): each XCD gets 64 consecutive tiles
  const int wg  = blockIdx.x;
  const int swz = ((wg & 7) << 6) + (wg >> 3);
  const int bx = swz & 31;          // M tile 0..31
  const int by = swz >> 5;          // N tile 0..15
  const int m0 = bx << 8;
  const int n0 = by << 8;

  const int tid  = threadIdx.x;
  const int wave = tid >> 6;        // 0..7
  const int lane = tid & 63;
  const int wm   = wave >> 2;       // 0..1 : M half (128 rows)
  const int wn   = wave & 3;        // 0..3 : N quarter (64 perm-cols)

  // ---- staging addresses: unit = 256 rows x 32 cols, 2 issues/thread ----
  // issue q: wave stages rows q*128 + wave*16 + (lane>>2); lane writes
  // phys slot lane&3; pre-swizzled source segment sgc = (lane&3)^((lane>>3)&3).
  const int srow = (wave << 4) + (lane >> 2);
  const int sgc  = (lane & 3) ^ ((lane >> 3) & 3);
  const __bf16* gA0 = A  + (size_t)(m0 + srow) * K2 + sgc * 8;
  const __bf16* gA1 = gA0 + (size_t)128 * K2;
  const __bf16* gB0 = Bt + (size_t)(n0 + srow) * K2 + sgc * 8;
  const __bf16* gB1 = gB0 + (size_t)128 * K2;

  // ---- fragment read offset (elems): row=(lane&15), slot=(lane>>4)^((lane>>1)&3)
  const int lane_part = ((lane & 15) << 5) + ((((lane >> 4) ^ ((lane >> 1) & 3))) << 3);

  f32x4 acc[8][4] = {};
  bf16x8 aF[4], bF[4];

  // ---- prologue: A0(0),B0(0),A1(0),B1(0),A0(1),B0(1)  (12 loads/thread) ----
  STAGE_A(0, 0, 0); STAGE_B(0, 0, 0);
  STAGE_A(0, 1, 0); STAGE_B(0, 1, 0);
  STAGE_A(1, 0, 1); STAGE_B(1, 0, 1);
  GATE8();                         // A0(0),B0(0) landed; 8 newest in flight
  __builtin_amdgcn_s_barrier();

  // ---- main loop: tiles 0 .. NT-3, steady-state gates vmcnt(8) ----
  for (int t = 0; t < NT - 2; ++t) {
    const int db = t & 1;
    // ph0 (kk=0, mh=0): stage A1(t+1) -> buf^1 kh1
    LOADA(db, 0, 0); LOADB(db, 0); STAGE_A(db ^ 1, 1, t + 1);
    BARW(); MFMA_Q(0); ENDBAR();
    // ph1 (kk=0, mh=1): stage B1(t+1); gate covers A1(t),B1(t)
    LOADA(db, 0, 1); STAGE_B(db ^ 1, 1, t + 1);
    BARW(); MFMA_Q(1); GATE8(); ENDBAR();
    // ph2 (kk=1, mh=0): stage A0(t+2) -> current buf kh0 (dead since ph1)
    LOADA(db, 1, 0); LOADB(db, 1); STAGE_A(db, 0, t + 2);
    BARW(); MFMA_Q(0); ENDBAR();
    // ph3 (kk=1, mh=1): stage B0(t+2); gate covers A0(t+1),B0(t+1)
    LOADA(db, 1, 1); STAGE_B(db, 0, t + 2);
    BARW(); MFMA_Q(1); GATE8(); ENDBAR();
  }

  // ---- tile NT-2 (buf 0): stage only A1/B1(NT-1); drain to 4 ----
  {
    LOADA(0, 0, 0); LOADB(0, 0); STAGE_A(1, 1, NT - 1);
    BARW(); MFMA_Q(0); ENDBAR();
    LOADA(0, 0, 1); STAGE_B(1, 1, NT - 1);
    BARW(); MFMA_Q(1); GATE8(); ENDBAR();
    LOADA(0, 1, 0); LOADB(0, 1);
    BARW(); MFMA_Q(0); ENDBAR();
    LOADA(0, 1, 1);
    BARW(); MFMA_Q(1); GATE4(); ENDBAR();
  }
  // ---- tile NT-1 (buf 1): no staging; drain to 0 after kk=0 ----
  {
    LOADA(1, 0, 0); LOADB(1, 0);
    BARW(); MFMA_Q(0); ENDBAR();
    LOADA(1, 0, 1);
    BARW(); MFMA_Q(1); GATE0(); ENDBAR();
    LOADA(1, 1, 0); LOADB(1, 1);
    BARW(); MFMA_Q(0); ENDBAR();
    LOADA(1, 1, 1);
    BARW(); MFMA_Q(1);
  }

  // ---- fused epilogue: gate == ni, lane-local ----
  // perm-col p = n0 + wn*64 + ni*16 + (lane&15) = (j>>4)*64 + gate*16 + (j&15)
  // -> j = by*64 + wn*16 + (lane&15), gate = ni.
  const int jj = (by << 6) + (wn << 4) + (lane & 15);
  const float vbi = bi[jj], vbf = bf_[jj], vbg = bg[jj], vbo = bo[jj];
  const int row_base = m0 + (wm << 7) + ((lane >> 4) << 2);
#pragma unroll
  for (int mi = 0; mi < 8; ++mi) {
#pragma unroll
    for (int r = 0; r < 4; ++r) {
      const int row = row_base + mi * 16 + r;
      const size_t idx = (size_t)row * H_DIM + jj;
      const float gi = sigm(acc[mi][0][r] + vbi);
      const float gf = sigm(acc[mi][1][r] + vbf);
      const float gg = tanh_fast(acc[mi][2][r] + vbg);
      const float go = sigm(acc[mi][3][r] + vbo);
      const float cv = c[idx];
      const float nc = gf * cv + gi * gg;
      out_c[idx] = nc;
      out_h[idx] = go * tanh_fast(nc);
    }
  }
}

extern "C" void kernel_launch(void* const* d_in, const int* in_sizes, int n_in,
                              void* d_out, int out_size, void* d_ws, size_t ws_size,
                              hipStream_t stream) {
  const float* x   = (const float*)d_in[0];
  const float* c   = (const float*)d_in[1];
  const float* h   = (const float*)d_in[2];
  const float* Wii = (const float*)d_in[3];
  const float* Wif = (const float*)d_in[4];
  const float* Wig = (const float*)d_in[5];
  const float* Wio = (const float*)d_in[6];
  const float* Whi = (const float*)d_in[7];
  const float* Whf = (const float*)d_in[8];
  const float* Whg = (const float*)d_in[9];
  const float* Who = (const float*)d_in[10];
  const float* bi  = (const float*)d_in[11];
  const float* bf_ = (const float*)d_in[12];
  const float* bg  = (const float*)d_in[13];
  const float* bo  = (const float*)d_in[14];

  __bf16* Abf = (__bf16*)d_ws;                                   // 32 MiB
  __bf16* Bt  = (__bf16*)((char*)d_ws + (size_t)B_DIM * K2 * 2); // 16 MiB

  float* out_c = (float*)d_out;
  float* out_h = out_c + (size_t)B_DIM * H_DIM;

  cast_a<<<B_DIM, 256, 0, stream>>>(x, h, Abf);
  dim3 gw(K2 / 64, H_DIM / 32, 4);
  cast_w<<<gw, 256, 0, stream>>>(Wii, Wif, Wig, Wio, Whi, Whf, Whg, Who, Bt);
  lstm_gemm<<<dim3((B_DIM / BM) * (N4 / BN)), 512, 0, stream>>>(
      Abf, Bt, c, bi, bf_, bg, bo, out_c, out_h);
}

// Round 2
// 335.360 us; speedup vs baseline: 1.0759x; 1.0759x over previous
//
#include <hip/hip_runtime.h>
#include <hip/hip_bf16.h>
#include <cstdint>

// LSTMCell B=8192, IN=H=1024, fp32 in/out.
// R5: 2-phase-per-K-tile schedule, ONE raw s_barrier per phase, counted
// vmcnt(8) gates, NO manual lgkmcnt/sched_barrier (compiler owns ds_read->
// MFMA waits). 2-tile unrolled loop -> all LDS indices compile-time.
// Cast kernels rewritten for 4x per-block work.

#define B_DIM 8192
#define H_DIM 1024
#define K2    2048   // IN + H
#define N4    4096   // 4 * H
#define BK    64
#define BM    256
#define BN    256
#define NT    (K2 / BK)   // 32 K-tiles (even; peel assumes it)

typedef __bf16 bf16x8 __attribute__((ext_vector_type(8)));
typedef float  f32x4  __attribute__((ext_vector_type(4)));

__device__ __forceinline__ void async_load16(const __bf16* g, __bf16* l) {
  __builtin_amdgcn_global_load_lds(
      (__attribute__((address_space(1))) void*)(g),
      (__attribute__((address_space(3))) void*)(l),
      16, 0, 0);
}

__device__ __forceinline__ float sigm(float x) {
  return 1.0f / (1.0f + __expf(-x));
}
__device__ __forceinline__ float tanh_fast(float x) {
  return 2.0f / (1.0f + __expf(-2.0f * x)) - 1.0f;
}

// ---------------- cast A = [x | h] -> bf16 [8192][2048] ----------------
// grid 2048, block 256: 4 rows per block
__global__ void cast_a(const float* __restrict__ x, const float* __restrict__ h,
                       __bf16* __restrict__ A) {
  const int r0 = blockIdx.x << 2;
  const int k = threadIdx.x << 3;  // 0..2040 step 8
  const float* base;
  int koff;
  if (k < H_DIM) { base = x; koff = k; } else { base = h; koff = k - H_DIM; }
#pragma unroll
  for (int r = 0; r < 4; ++r) {
    const int row = r0 + r;
    const float* src = base + (size_t)row * H_DIM + koff;
    float4 v0 = *(const float4*)src;
    float4 v1 = *(const float4*)(src + 4);
    bf16x8 o;
    o[0] = (__bf16)v0.x; o[1] = (__bf16)v0.y; o[2] = (__bf16)v0.z; o[3] = (__bf16)v0.w;
    o[4] = (__bf16)v1.x; o[5] = (__bf16)v1.y; o[6] = (__bf16)v1.z; o[7] = (__bf16)v1.w;
    *(bf16x8*)&A[(size_t)row * K2 + k] = o;
  }
}

// ------------- cast + transpose + permute weights -> Bt [4096][2048] -------------
// Bt row p = (j>>4)*64 + gate*16 + (j&15); Bt[p][k] = W_cat[k][gate-col j]
// grid: (K2/64=32, H/128=8, 4 gates) = 1024 blocks, block 256.
// Per block: 64k x 128j fp32 tile (32 KiB read, 16 KiB write).
__global__ void cast_w(const float* __restrict__ Wii, const float* __restrict__ Wif,
                       const float* __restrict__ Wig, const float* __restrict__ Wio,
                       const float* __restrict__ Whi, const float* __restrict__ Whf,
                       const float* __restrict__ Whg, const float* __restrict__ Who,
                       __bf16* __restrict__ Bt) {
  __shared__ float tile[64][132];   // 132: 16B-aligned rows, bank-spread
  const int k0 = blockIdx.x * 64;
  const int j0 = blockIdx.y * 128;
  const int gate = blockIdx.z;
  const float* Wi[4] = {Wii, Wif, Wig, Wio};
  const float* Wh[4] = {Whi, Whf, Whg, Who};
  const float* W = (k0 < H_DIM) ? Wi[gate] : Wh[gate];
  const int kb = (k0 < H_DIM) ? k0 : (k0 - H_DIM);

  const int rr = threadIdx.x >> 3;   // 0..31
  const int cs = threadIdx.x & 7;    // float4 seg group
#pragma unroll
  for (int pass = 0; pass < 2; ++pass) {
    const int r = rr + pass * 32;
    const float* src = W + (size_t)(kb + r) * H_DIM + j0;
#pragma unroll
    for (int i = 0; i < 4; ++i) {
      float4 v = *(const float4*)(src + (cs + 8 * i) * 4);
      *(float4*)&tile[r][(cs + 8 * i) * 4] = v;
    }
  }
  __syncthreads();

  const int jl = threadIdx.x >> 1;         // 0..127
  const int kc = (threadIdx.x & 1) * 32;   // 0 or 32
  const int j  = j0 + jl;
  const int p  = ((j >> 4) << 6) + (gate << 4) + (j & 15);
  __bf16* dst = Bt + (size_t)p * K2 + k0 + kc;
#pragma unroll
  for (int cch = 0; cch < 4; ++cch) {
    bf16x8 o;
#pragma unroll
    for (int e = 0; e < 8; ++e) o[e] = (__bf16)tile[kc + cch * 8 + e][jl];
    *(bf16x8*)&dst[cch * 8] = o;
  }
}

// ---------------- fused GEMM + LSTM gate epilogue ----------------
// grid: 512 blocks (32 M-tiles x 16 N-tiles), block 512 (8 waves, 2M x 4N)
// Per phase (2 per K-tile): 12 ds_read_b128 | 4 global_load_lds | 32 MFMA
//                           | vmcnt(8) | s_barrier.

#define STAGE_A(D, KH, TT) do { \
    async_load16(gA0 + (size_t)(TT) * 64 + (KH) * 32, &As_s[D][KH][wave << 9]); \
    async_load16(gA1 + (size_t)(TT) * 64 + (KH) * 32, &As_s[D][KH][4096 + (wave << 9)]); \
  } while (0)
#define STAGE_B(D, KH, TT) do { \
    async_load16(gB0 + (size_t)(TT) * 64 + (KH) * 32, &Bs_s[D][KH][wave << 9]); \
    async_load16(gB1 + (size_t)(TT) * 64 + (KH) * 32, &Bs_s[D][KH][4096 + (wave << 9)]); \
  } while (0)
#define STAGE_AB(D, KH, TT) do { STAGE_A(D, KH, TT); STAGE_B(D, KH, TT); } while (0)

#define DS_LOADS(DB, KK) do { \
    const __bf16* ap_ = &As_s[DB][KK][(wm << 12) + lane_part]; \
    const __bf16* bp_ = &Bs_s[DB][KK][(wn << 11) + lane_part]; \
    aF0[0] = *(const bf16x8*)(ap_);          aF0[1] = *(const bf16x8*)(ap_ + 512); \
    aF0[2] = *(const bf16x8*)(ap_ + 1024);   aF0[3] = *(const bf16x8*)(ap_ + 1536); \
    aF1[0] = *(const bf16x8*)(ap_ + 2048);   aF1[1] = *(const bf16x8*)(ap_ + 2560); \
    aF1[2] = *(const bf16x8*)(ap_ + 3072);   aF1[3] = *(const bf16x8*)(ap_ + 3584); \
    bF[0]  = *(const bf16x8*)(bp_);          bF[1]  = *(const bf16x8*)(bp_ + 512); \
    bF[2]  = *(const bf16x8*)(bp_ + 1024);   bF[3]  = *(const bf16x8*)(bp_ + 1536); \
  } while (0)

#define MFMA32() do { \
    __builtin_amdgcn_s_setprio(1); \
    _Pragma("unroll") \
    for (int i2 = 0; i2 < 4; ++i2) { \
      _Pragma("unroll") \
      for (int n2 = 0; n2 < 4; ++n2) \
        acc[i2][n2] = __builtin_amdgcn_mfma_f32_16x16x32_bf16( \
            aF0[i2], bF[n2], acc[i2][n2], 0, 0, 0); \
    } \
    _Pragma("unroll") \
    for (int i2 = 0; i2 < 4; ++i2) { \
      _Pragma("unroll") \
      for (int n2 = 0; n2 < 4; ++n2) \
        acc[4 + i2][n2] = __builtin_amdgcn_mfma_f32_16x16x32_bf16( \
            aF1[i2], bF[n2], acc[4 + i2][n2], 0, 0, 0); \
    } \
    __builtin_amdgcn_s_setprio(0); \
  } while (0)

#define GATE(N) asm volatile("s_waitcnt vmcnt(" #N ")" ::: "memory")

#define PHASE(DB, KK, STG, GT) do { \
    DS_LOADS(DB, KK); \
    STG; \
    MFMA32(); \
    GT; \
    __builtin_amdgcn_s_barrier(); \
  } while (0)

__global__ __launch_bounds__(512, 2) void lstm_gemm(
    const __bf16* __restrict__ A,    // [8192][2048]
    const __bf16* __restrict__ Bt,   // [4096][2048] permuted rows
    const float* __restrict__ c,
    const float* __restrict__ bi, const float* __restrict__ bf_,
    const float* __restrict__ bg, const float* __restrict__ bo,
    float* __restrict__ out_c, float* __restrict__ out_h) {
  // [buf][khalf][256 rows][32 cols] bf16; row = 64 B = 4 x 16B slots.
  // phys slot s of row r holds global k-segment s ^ ((r>>1)&3).
  __shared__ __align__(16) __bf16 As_s[2][2][256 * 32];   // 64 KB
  __shared__ __align__(16) __bf16 Bs_s[2][2][256 * 32];   // 64 KB

  // bijective XCD swizzle (512 % 8 == 0)
  const int wg  = blockIdx.x;
  const int swz = ((wg & 7) << 6) + (wg >> 3);
  const int bx = swz & 31;          // M tile 0..31
  const int by = swz >> 5;          // N tile 0..15
  const int m0 = bx << 8;
  const int n0 = by << 8;

  const int tid  = threadIdx.x;
  const int wave = tid >> 6;        // 0..7
  const int lane = tid & 63;
  const int wm   = wave >> 2;       // 0..1 : M half (128 rows)
  const int wn   = wave & 3;        // 0..3 : N quarter (64 perm-cols)

  // staging: wave w stages rows w*16+(lane>>2) of each 128-row half; lane
  // writes phys slot lane&3; pre-swizzled source seg = (lane&3)^((lane>>3)&3).
  const int srow = (wave << 4) + (lane >> 2);
  const int sgc  = (lane & 3) ^ ((lane >> 3) & 3);
  const __bf16* gA0 = A  + (size_t)(m0 + srow) * K2 + sgc * 8;
  const __bf16* gA1 = gA0 + (size_t)128 * K2;
  const __bf16* gB0 = Bt + (size_t)(n0 + srow) * K2 + sgc * 8;
  const __bf16* gB1 = gB0 + (size_t)128 * K2;

  // fragment read offset (elems): row=(lane&15), slot=(lane>>4)^((lane>>1)&3)
  const int lane_part = ((lane & 15) << 5) + ((((lane >> 4) ^ ((lane >> 1) & 3))) << 3);

  f32x4 acc[8][4] = {};
  bf16x8 aF0[4], aF1[4], bF[4];

  // ---- prologue: A0B0(0), A1B1(0), A0B0(1) -> 12 loads/thread ----
  STAGE_AB(0, 0, 0);
  STAGE_AB(0, 1, 0);
  STAGE_AB(1, 0, 1);
  GATE(8);                          // A0B0(0) landed
  __builtin_amdgcn_s_barrier();

  // ---- main loop, 2 tiles/iter (static buffer indices) ----
  for (int t = 0; t < NT - 2; t += 2) {
    PHASE(0, 0, STAGE_AB(1, 1, t + 1), GATE(8));   // tile t   kh0
    PHASE(0, 1, STAGE_AB(0, 0, t + 2), GATE(8));   // tile t   kh1
    PHASE(1, 0, STAGE_AB(0, 1, t + 2), GATE(8));   // tile t+1 kh0
    PHASE(1, 1, STAGE_AB(1, 0, t + 3), GATE(8));   // tile t+1 kh1
  }
  // ---- peel tiles NT-2 (buf0), NT-1 (buf1) ----
  PHASE(0, 0, STAGE_AB(1, 1, NT - 1), GATE(8));
  PHASE(0, 1, (void)0, GATE(4));
  PHASE(1, 0, (void)0, GATE(0));
  DS_LOADS(1, 1);
  MFMA32();

  // ---- fused epilogue: gate == n-fragment index, lane-local ----
  // p = n0 + wn*64 + ni*16 + (lane&15)  ->  j = by*64 + wn*16 + (lane&15)
  const int jj = (by << 6) + (wn << 4) + (lane & 15);
  const float vbi = bi[jj], vbf = bf_[jj], vbg = bg[jj], vbo = bo[jj];
  const int row_base = m0 + (wm << 7) + ((lane >> 4) << 2);
#pragma unroll
  for (int mi = 0; mi < 8; ++mi) {
#pragma unroll
    for (int r = 0; r < 4; ++r) {
      const int row = row_base + mi * 16 + r;
      const size_t idx = (size_t)row * H_DIM + jj;
      const float gi = sigm(acc[mi][0][r] + vbi);
      const float gf = sigm(acc[mi][1][r] + vbf);
      const float gg = tanh_fast(acc[mi][2][r] + vbg);
      const float go = sigm(acc[mi][3][r] + vbo);
      const float cv = c[idx];
      const float nc = gf * cv + gi * gg;
      out_c[idx] = nc;
      out_h[idx] = go * tanh_fast(nc);
    }
  }
}

extern "C" void kernel_launch(void* const* d_in, const int* in_sizes, int n_in,
                              void* d_out, int out_size, void* d_ws, size_t ws_size,
                              hipStream_t stream) {
  const float* x   = (const float*)d_in[0];
  const float* c   = (const float*)d_in[1];
  const float* h   = (const float*)d_in[2];
  const float* Wii = (const float*)d_in[3];
  const float* Wif = (const float*)d_in[4];
  const float* Wig = (const float*)d_in[5];
  const float* Wio = (const float*)d_in[6];
  const float* Whi = (const float*)d_in[7];
  const float* Whf = (const float*)d_in[8];
  const float* Whg = (const float*)d_in[9];
  const float* Who = (const float*)d_in[10];
  const float* bi  = (const float*)d_in[11];
  const float* bf_ = (const float*)d_in[12];
  const float* bg  = (const float*)d_in[13];
  const float* bo  = (const float*)d_in[14];

  __bf16* Abf = (__bf16*)d_ws;                                   // 32 MiB
  __bf16* Bt  = (__bf16*)((char*)d_ws + (size_t)B_DIM * K2 * 2); // 16 MiB

  float* out_c = (float*)d_out;
  float* out_h = out_c + (size_t)B_DIM * H_DIM;

  cast_a<<<B_DIM / 4, 256, 0, stream>>>(x, h, Abf);
  dim3 gw(K2 / 64, H_DIM / 128, 4);
  cast_w<<<gw, 256, 0, stream>>>(Wii, Wif, Wig, Wio, Whi, Whf, Whg, Who, Bt);
  lstm_gemm<<<dim3((B_DIM / BM) * (N4 / BN)), 512, 0, stream>>>(
      Abf, Bt, c, bi, bf_, bg, bo, out_c, out_h);
}